// Round 7
// baseline (161.699 us; speedup 1.0000x reference)
//
#include <hip/hip_runtime.h>
#include <hip/hip_bf16.h>

// Problem constants: B=32, N=128, H=32, NP1=129, NUM_EDGES+1=1537, MHMD=5.
#define BB 32
#define NN 128
#define HH 32
#define NP1 129
#define NE1 1537
#define MHMD 5
#define HG 4            // heads per block
#define NHG (HH / HG)   // 8 h-groups

// ws layout: Mt bf16 [NHG][MHMD][NE1][HG]   = 491,840 B
//            spwT f32 [NHG][512][HG]        =  65,536 B   (total 557,376 B)

// ---------------------------------------------------------------------------
// Kernel 1a: Mt[hg][d][r][hl] = bf16( sum_h E[r][h] * Wd[d][h][4hg+hl] )
// ---------------------------------------------------------------------------
__global__ __launch_bounds__(256) void precompute_Mt(const float* __restrict__ E,
                                                     const float* __restrict__ W,
                                                     __hip_bfloat16* __restrict__ Mt) {
    int idx = blockIdx.x * 256 + threadIdx.x;      // d*NE1*HH + r*HH + k
    if (idx >= MHMD * NE1 * HH) return;
    int k = idx & 31;
    int r = (idx >> 5) % NE1;
    int d = idx / (NE1 * HH);
    const float* wd = W + d * HH * HH;
    float acc = 0.f;
#pragma unroll
    for (int h = 0; h < HH; ++h)
        acc += E[r * HH + h] * wd[h * HH + k];
    int hg = k >> 2, hl = k & 3;
    Mt[(((size_t)hg * MHMD + d) * NE1 + r) * HG + hl] = __float2bfloat16(acc);
}

// ---------------------------------------------------------------------------
// Kernel 1b: spwT[hg][s][hl] = spw[s][4hg+hl]   (f32, keeps spatial term exact)
// ---------------------------------------------------------------------------
__global__ __launch_bounds__(256) void precompute_spwT(const float* __restrict__ spw,
                                                       float* __restrict__ spwT) {
    int idx = blockIdx.x * 256 + threadIdx.x;      // s*32 + k
    if (idx >= 512 * HH) return;
    int k = idx & 31, s = idx >> 5;
    spwT[(((k >> 2) * 512) + s) * HG + (k & 3)] = spw[idx];
}

// ---------------------------------------------------------------------------
// Kernel 2: borders. g[b,h,0,:] and g[b,h,1:,0] = 2*ab + t[h]
// ---------------------------------------------------------------------------
__global__ __launch_bounds__(256) void border_kernel(const float* __restrict__ ab,
                                                     const float* __restrict__ tvd,
                                                     float* __restrict__ out) {
    int idx = blockIdx.x * 256 + threadIdx.x;
    if (idx >= BB * HH * 257) return;
    int pos = idx % 257;
    int bh  = idx / 257;
    int h = bh & 31, b = bh >> 5;
    int r, c;
    if (pos < NP1) { r = 0; c = pos; }
    else           { r = pos - 128; c = 0; }
    float v = 2.0f * ab[((size_t)b * NP1 + r) * NP1 + c] + tvd[h];
    out[(((size_t)b * HH + h) * NP1 + r) * NP1 + c] = v;
}

// ---------------------------------------------------------------------------
// Kernel 3: inner cells, LDS-gather design.
// Block = (b, hg, ihalf): bid = ihalf*256 + hg*32 + b  ->  bid%8 == b%8, so
// the 16 blocks sharing b land on one XCD (round-robin dispatch) and edge[b]
// (983 KB) stays L2-resident (4 b's/XCD ~= 3.9 MB ~ L2).
// Stage M 4-head slice (61.5 KB bf16) + spw slice (8 KB f32) in LDS; each
// cell does 15 ds_read_b64 gathers serving 4 heads. No divergent global
// loads anywhere; edge/spatial/ab reads and all stores are coalesced.
// ---------------------------------------------------------------------------
__global__ __launch_bounds__(1024) void inner_kernel(const float* __restrict__ ab,
                                                     const int* __restrict__ spatial,
                                                     const int* __restrict__ edge_input,
                                                     const __hip_bfloat16* __restrict__ Mt,
                                                     const float* __restrict__ spwT,
                                                     float* __restrict__ out) {
    __shared__ uint2  sM[MHMD * NE1];   // 61,480 B : [d][r] -> 4 bf16 heads
    __shared__ float4 sS[512];          //  8,192 B : [s]    -> 4 f32 heads

    const int bid   = blockIdx.x;
    const int b     = bid & 31;
    const int hg    = (bid >> 5) & 7;
    const int ihalf = bid >> 8;
    const int t     = threadIdx.x;

    // --- stage M slice (15,370 dwords) and spw slice (512 float4) ---
    const uint* msrc = (const uint*)(Mt + (size_t)hg * MHMD * NE1 * HG);
    uint* mdst = (uint*)sM;
    for (int x = t; x < (MHMD * NE1 * HG) / 2; x += 1024)
        mdst[x] = msrc[x];
    const float4* ssrc = (const float4*)(spwT + (size_t)hg * 512 * HG);
    if (t < 512) sS[t] = ssrc[t];
    __syncthreads();

    const int*   eb   = edge_input + (size_t)b * NN * NN * 15;
    const int*   spb  = spatial    + (size_t)b * NN * NN;
    const float* abb  = ab         + (size_t)b * NP1 * NP1;
    float*       outb = out + ((size_t)(b * HH + hg * HG)) * NP1 * NP1;
    const size_t PL = (size_t)NP1 * NP1;   // plane stride

#pragma unroll
    for (int c = 0; c < 8; ++c) {
        int cell = ihalf * 8192 + c * 1024 + t;    // 64 i's x 128 j's
        int i = cell >> 7, j = cell & 127;
        const int* ep = eb + (size_t)cell * 15;
        int e[15];
#pragma unroll
        for (int p = 0; p < 15; ++p) e[p] = ep[p];

        float a0 = 0.f, a1 = 0.f, a2 = 0.f, a3 = 0.f;
#pragma unroll
        for (int p = 0; p < 15; ++p) {
            uint2 v = sM[(p / 3) * NE1 + e[p]];    // ds_read_b64, 4 heads
            a0 += __uint_as_float(v.x << 16);
            a1 += __uint_as_float(v.x & 0xffff0000u);
            a2 += __uint_as_float(v.y << 16);
            a3 += __uint_as_float(v.y & 0xffff0000u);
        }
        int sp  = spb[cell];
        int sp1 = sp <= 1 ? 1 : min(sp - 1, MHMD);
        // 1/(3*sp1): v_rcp_f32 (~1e-6 rel err, invisible vs 0.03 tolerance)
        float m = __builtin_amdgcn_rcpf(3.0f * (float)sp1);
        float4 sw = sS[sp];
        float av  = 2.0f * abb[(i + 1) * NP1 + (j + 1)];
        size_t o  = (size_t)(i + 1) * NP1 + (j + 1);
        outb[o]          = av + sw.x + a0 * m;
        outb[o + PL]     = av + sw.y + a1 * m;
        outb[o + 2 * PL] = av + sw.z + a2 * m;
        outb[o + 3 * PL] = av + sw.w + a3 * m;
    }
}

// ---------------------------------------------------------------------------
// Fallback (only if ws_size too small): direct per-output computation.
// ---------------------------------------------------------------------------
__global__ __launch_bounds__(256) void inner_direct(const float* __restrict__ ab,
                                                    const int* __restrict__ spatial,
                                                    const int* __restrict__ edge_input,
                                                    const float* __restrict__ E,
                                                    const float* __restrict__ W,
                                                    const float* __restrict__ spw,
                                                    float* __restrict__ out) {
    long idx = (long)blockIdx.x * 256 + threadIdx.x;
    if (idx >= (long)BB * NN * NN * HH) return;
    int h = idx & 31;
    long cell = idx >> 5;
    int j  = cell & 127;
    int bi = (int)(cell >> 7);
    int i  = bi & 127;
    int b  = bi >> 7;
    const int* e = edge_input + cell * 15;
    float acc = 0.f;
    for (int d = 0; d < MHMD; ++d) {
        const float* wd = W + d * HH * HH;
        int e0 = e[d * 3 + 0] * HH, e1 = e[d * 3 + 1] * HH, e2 = e[d * 3 + 2] * HH;
        for (int hp = 0; hp < HH; ++hp) {
            float eh = E[e0 + hp] + E[e1 + hp] + E[e2 + hp];
            acc += eh * wd[hp * HH + h];
        }
    }
    int spd = spatial[cell];
    int sp1 = spd == 0 ? 1 : spd;
    sp1 = sp1 > 1 ? sp1 - 1 : sp1;
    sp1 = sp1 > MHMD ? MHMD : sp1;
    float v = spw[spd * HH + h] + acc / (3.0f * (float)sp1);
    out[(((size_t)b * HH + h) * NP1 + (i + 1)) * NP1 + (j + 1)] =
        2.0f * ab[((size_t)b * NP1 + (i + 1)) * NP1 + (j + 1)] + v;
}

extern "C" void kernel_launch(void* const* d_in, const int* in_sizes, int n_in,
                              void* d_out, int out_size, void* d_ws, size_t ws_size,
                              hipStream_t stream) {
    const float* ab      = (const float*)d_in[0];
    const int*   spatial = (const int*)  d_in[1];
    const int*   edge_in = (const int*)  d_in[3];
    const float* E       = (const float*)d_in[5];
    const float* W       = (const float*)d_in[6];
    const float* spw     = (const float*)d_in[7];
    const float* tvd     = (const float*)d_in[8];
    float* out = (float*)d_out;

    border_kernel<<<(BB * HH * 257 + 255) / 256, 256, 0, stream>>>(ab, tvd, out);

    const size_t Mt_bytes  = (size_t)NHG * MHMD * NE1 * HG * sizeof(__hip_bfloat16); // 491,840
    const size_t spw_bytes = (size_t)NHG * 512 * HG * sizeof(float);                 //  65,536
    if (ws_size >= Mt_bytes + spw_bytes) {
        __hip_bfloat16* Mt  = (__hip_bfloat16*)d_ws;
        float*          spT = (float*)((char*)d_ws + Mt_bytes);   // 16B-aligned
        precompute_Mt<<<(MHMD * NE1 * HH + 255) / 256, 256, 0, stream>>>(E, W, Mt);
        precompute_spwT<<<(512 * HH + 255) / 256, 256, 0, stream>>>(spw, spT);
        inner_kernel<<<512, 1024, 0, stream>>>(ab, spatial, edge_in, Mt, spT, out);
    } else {
        long total = (long)BB * NN * NN * HH;
        inner_direct<<<(unsigned)((total + 255) / 256), 256, 0, stream>>>(
            ab, spatial, edge_in, E, W, spw, out);
    }
}

// Round 9
// 158.679 us; speedup vs baseline: 1.0190x; 1.0190x over previous
//
#include <hip/hip_runtime.h>
#include <hip/hip_bf16.h>

// Problem constants: B=32, N=128, H=32, NP1=129, NUM_EDGES+1=1537, MHMD=5.
#define BB 32
#define NN 128
#define HH 32
#define NP1 129
#define NE1 1537
#define MHMD 5
#define HG 4            // heads per block
#define NHG (HH / HG)   // 8 h-groups

// ws layout: Mt bf16 [NHG][MHMD][NE1][HG]   = 491,840 B
//            spwT f32 [NHG][512][HG]        =  65,536 B   (total 557,376 B)

// ---------------------------------------------------------------------------
// Kernel 1a: Mt[hg][d][r][hl] = bf16( sum_h E[r][h] * Wd[d][h][4hg+hl] )
// ---------------------------------------------------------------------------
__global__ __launch_bounds__(256) void precompute_Mt(const float* __restrict__ E,
                                                     const float* __restrict__ W,
                                                     __hip_bfloat16* __restrict__ Mt) {
    int idx = blockIdx.x * 256 + threadIdx.x;      // d*NE1*HH + r*HH + k
    if (idx >= MHMD * NE1 * HH) return;
    int k = idx & 31;
    int r = (idx >> 5) % NE1;
    int d = idx / (NE1 * HH);
    const float* wd = W + d * HH * HH;
    float acc = 0.f;
#pragma unroll
    for (int h = 0; h < HH; ++h)
        acc += E[r * HH + h] * wd[h * HH + k];
    int hg = k >> 2, hl = k & 3;
    Mt[(((size_t)hg * MHMD + d) * NE1 + r) * HG + hl] = __float2bfloat16(acc);
}

// ---------------------------------------------------------------------------
// Kernel 1b: spwT[hg][s][hl] = spw[s][4hg+hl]
// ---------------------------------------------------------------------------
__global__ __launch_bounds__(256) void precompute_spwT(const float* __restrict__ spw,
                                                       float* __restrict__ spwT) {
    int idx = blockIdx.x * 256 + threadIdx.x;      // s*32 + k
    if (idx >= 512 * HH) return;
    int k = idx & 31, s = idx >> 5;
    spwT[(((k >> 2) * 512) + s) * HG + (k & 3)] = spw[idx];
}

// ---------------------------------------------------------------------------
// Kernel 2: borders. g[b,h,0,:] and g[b,h,1:,0] = 2*ab + t[h]
// ---------------------------------------------------------------------------
__global__ __launch_bounds__(256) void border_kernel(const float* __restrict__ ab,
                                                     const float* __restrict__ tvd,
                                                     float* __restrict__ out) {
    int idx = blockIdx.x * 256 + threadIdx.x;
    if (idx >= BB * HH * 257) return;
    int pos = idx % 257;
    int bh  = idx / 257;
    int h = bh & 31, b = bh >> 5;
    int r, c;
    if (pos < NP1) { r = 0; c = pos; }
    else           { r = pos - 128; c = 0; }
    float v = 2.0f * ab[((size_t)b * NP1 + r) * NP1 + c] + tvd[h];
    out[(((size_t)b * HH + h) * NP1 + r) * NP1 + c] = v;
}

// ---------------------------------------------------------------------------
// Kernel 3: inner cells. Block = (b, hg, ihalf), 1024 threads, 8192 cells.
// All VMEM coalesced:
//   - M 4-head slice (61.5 KB bf16) + spw slice staged once in LDS
//   - edge indices staged per-1024-cell chunk via int4 (register-prefetched
//     one chunk ahead so HBM latency hides under compute)
//   - per cell: 15 ds_read_b32 edge (stride-15 => 2 lanes/bank, free) +
//     15 ds_read_b64 M-gather + coalesced sp/ab loads + 4 coalesced stores.
// bid = ihalf*256 + hg*32 + b -> bid%8 == b%8: blocks sharing b colocate on
// one XCD (round-robin dispatch) so edge[b] stays L2-resident.
// ---------------------------------------------------------------------------
__global__ __launch_bounds__(1024) void inner_kernel(const float* __restrict__ ab,
                                                     const int* __restrict__ spatial,
                                                     const int* __restrict__ edge_input,
                                                     const __hip_bfloat16* __restrict__ Mt,
                                                     const float* __restrict__ spwT,
                                                     float* __restrict__ out) {
    __shared__ uint2  sM[MHMD * NE1];   // 61,480 B : [d][r] -> 4 bf16 heads
    __shared__ float4 sS[512];          //  8,192 B : [s]    -> 4 f32 heads
    __shared__ int    sE[1024 * 15];    // 61,440 B : one chunk of edge indices

    const int bid   = blockIdx.x;
    const int b     = bid & 31;
    const int hg    = (bid >> 5) & 7;
    const int ihalf = bid >> 8;
    const int t     = threadIdx.x;

    // --- stage M slice and spw slice (coalesced) ---
    const uint* msrc = (const uint*)(Mt + (size_t)hg * MHMD * NE1 * HG);
    uint* mdst = (uint*)sM;
    for (int x = t; x < (MHMD * NE1 * HG) / 2; x += 1024)
        mdst[x] = msrc[x];
    const float4* ssrc = (const float4*)(spwT + (size_t)hg * 512 * HG);
    if (t < 512) sS[t] = ssrc[t];

    const int*   spb  = spatial + (size_t)b * NN * NN;
    const float* abb  = ab      + (size_t)b * NP1 * NP1;
    float*       outb = out + ((size_t)(b * HH + hg * HG)) * NP1 * NP1;
    const size_t PL = (size_t)NP1 * NP1;   // plane stride

    // edge source for this (b, ihalf): 8 chunks x 3840 int4
    const int4* esrc = (const int4*)(edge_input
                     + (size_t)b * NN * NN * 15 + (size_t)ihalf * 8192 * 15);

    // --- prefetch chunk 0 into registers ---
    int4 pf0, pf1, pf2, pf3;
    {
        pf0 = esrc[t];
        pf1 = esrc[1024 + t];
        pf2 = esrc[2048 + t];
        pf3 = (3072 + t < 3840) ? esrc[3072 + t] : make_int4(0, 0, 0, 0);
    }

    for (int ch = 0; ch < 8; ++ch) {
        // write prefetched chunk to LDS
        int4* ed = (int4*)sE;
        ed[t]        = pf0;
        ed[1024 + t] = pf1;
        ed[2048 + t] = pf2;
        if (3072 + t < 3840) ed[3072 + t] = pf3;
        __syncthreads();

        // issue next chunk's loads (in flight during compute)
        if (ch < 7) {
            const int4* nsrc = esrc + (ch + 1) * 3840;
            pf0 = nsrc[t];
            pf1 = nsrc[1024 + t];
            pf2 = nsrc[2048 + t];
            pf3 = (3072 + t < 3840) ? nsrc[3072 + t] : make_int4(0, 0, 0, 0);
        }

        // --- compute my cell ---
        const int cell = ihalf * 8192 + ch * 1024 + t;
        const int i = cell >> 7, j = cell & 127;

        // coalesced scalar loads, issued early
        const int   sp = spb[cell];
        const float av = 2.0f * abb[(i + 1) * NP1 + (j + 1)];

        int e[15];
#pragma unroll
        for (int p = 0; p < 15; ++p) e[p] = sE[t * 15 + p];   // stride-15: free

        uint2 v[15];
#pragma unroll
        for (int p = 0; p < 15; ++p)
            v[p] = sM[(p / 3) * NE1 + e[p]];                  // ds_read_b64

        float a0 = 0.f, a1 = 0.f, a2 = 0.f, a3 = 0.f;
#pragma unroll
        for (int p = 0; p < 15; ++p) {
            a0 += __uint_as_float(v[p].x << 16);
            a1 += __uint_as_float(v[p].x & 0xffff0000u);
            a2 += __uint_as_float(v[p].y << 16);
            a3 += __uint_as_float(v[p].y & 0xffff0000u);
        }
        const int sp1 = sp <= 1 ? 1 : min(sp - 1, MHMD);
        const float m = __builtin_amdgcn_rcpf(3.0f * (float)sp1);
        const float4 sw = sS[sp];

        const size_t o = (size_t)(i + 1) * NP1 + (j + 1);
        outb[o]          = av + sw.x + a0 * m;
        outb[o + PL]     = av + sw.y + a1 * m;
        outb[o + 2 * PL] = av + sw.z + a2 * m;
        outb[o + 3 * PL] = av + sw.w + a3 * m;
        __syncthreads();   // protect sE before next chunk's write
    }
}

// ---------------------------------------------------------------------------
// Fallback (only if ws_size too small): direct per-output computation.
// ---------------------------------------------------------------------------
__global__ __launch_bounds__(256) void inner_direct(const float* __restrict__ ab,
                                                    const int* __restrict__ spatial,
                                                    const int* __restrict__ edge_input,
                                                    const float* __restrict__ E,
                                                    const float* __restrict__ W,
                                                    const float* __restrict__ spw,
                                                    float* __restrict__ out) {
    long idx = (long)blockIdx.x * 256 + threadIdx.x;
    if (idx >= (long)BB * NN * NN * HH) return;
    int h = idx & 31;
    long cell = idx >> 5;
    int j  = cell & 127;
    int bi = (int)(cell >> 7);
    int i  = bi & 127;
    int b  = bi >> 7;
    const int* e = edge_input + cell * 15;
    float acc = 0.f;
    for (int d = 0; d < MHMD; ++d) {
        const float* wd = W + d * HH * HH;
        int e0 = e[d * 3 + 0] * HH, e1 = e[d * 3 + 1] * HH, e2 = e[d * 3 + 2] * HH;
        for (int hp = 0; hp < HH; ++hp) {
            float eh = E[e0 + hp] + E[e1 + hp] + E[e2 + hp];
            acc += eh * wd[hp * HH + h];
        }
    }
    int spd = spatial[cell];
    int sp1 = spd == 0 ? 1 : spd;
    sp1 = sp1 > 1 ? sp1 - 1 : sp1;
    sp1 = sp1 > MHMD ? MHMD : sp1;
    float v = spw[spd * HH + h] + acc / (3.0f * (float)sp1);
    out[(((size_t)b * HH + h) * NP1 + (i + 1)) * NP1 + (j + 1)] =
        2.0f * ab[((size_t)b * NP1 + (i + 1)) * NP1 + (j + 1)] + v;
}

extern "C" void kernel_launch(void* const* d_in, const int* in_sizes, int n_in,
                              void* d_out, int out_size, void* d_ws, size_t ws_size,
                              hipStream_t stream) {
    const float* ab      = (const float*)d_in[0];
    const int*   spatial = (const int*)  d_in[1];
    const int*   edge_in = (const int*)  d_in[3];
    const float* E       = (const float*)d_in[5];
    const float* W       = (const float*)d_in[6];
    const float* spw     = (const float*)d_in[7];
    const float* tvd     = (const float*)d_in[8];
    float* out = (float*)d_out;

    border_kernel<<<(BB * HH * 257 + 255) / 256, 256, 0, stream>>>(ab, tvd, out);

    const size_t Mt_bytes  = (size_t)NHG * MHMD * NE1 * HG * sizeof(__hip_bfloat16); // 491,840
    const size_t spw_bytes = (size_t)NHG * 512 * HG * sizeof(float);                 //  65,536
    if (ws_size >= Mt_bytes + spw_bytes) {
        __hip_bfloat16* Mt  = (__hip_bfloat16*)d_ws;
        float*          spT = (float*)((char*)d_ws + Mt_bytes);
        precompute_Mt<<<(MHMD * NE1 * HH + 255) / 256, 256, 0, stream>>>(E, W, Mt);
        precompute_spwT<<<(512 * HH + 255) / 256, 256, 0, stream>>>(spw, spT);
        inner_kernel<<<512, 1024, 0, stream>>>(ab, spatial, edge_in, Mt, spT, out);
    } else {
        long total = (long)BB * NN * NN * HH;
        inner_direct<<<(unsigned)((total + 255) / 256), 256, 0, stream>>>(
            ab, spatial, edge_in, E, W, spw, out);
    }
}